// Round 1
// 321.689 us; speedup vs baseline: 1.0227x; 1.0227x over previous
//
#include <hip/hip_runtime.h>
#include <stdint.h>
#include <math.h>

typedef __attribute__((ext_vector_type(8))) short short8;
typedef __attribute__((ext_vector_type(4))) float f32x4;

__device__ __forceinline__ ushort f2bf(float f) {
    union { float f; uint32_t i; } v; v.f = f;
    uint32_t r = v.i + 0x7FFFu + ((v.i >> 16) & 1u);
    return (ushort)(r >> 16);
}
__device__ __forceinline__ float bf2f(ushort u) {
    union { uint32_t i; float f; } v; v.i = ((uint32_t)u) << 16; return v.f;
}

// ---------------------------------------------------------------------------
// Kernel 1: input transpose [B,T,C,L] (f32) -> x[token][c] (f32) + LN1 -> xln (bf16)
// one block per token (4096 blocks x 512 threads)
__global__ __launch_bounds__(512) void prep_kernel(const float* __restrict__ in,
        const float* __restrict__ g, const float* __restrict__ bta,
        float* __restrict__ x, ushort* __restrict__ xln) {
    int token = blockIdx.x;          // 0..4095
    int c = threadIdx.x;             // 0..511
    int b = token >> 11;
    int n = token & 2047;
    int t = n >> 8;
    int l = n & 255;
    size_t iidx = (((size_t)((b * 8 + t) * 512 + c)) << 8) + l;
    float v = in[iidx];
    x[(size_t)token * 512 + c] = v;

    float s = v, s2 = v * v;
    #pragma unroll
    for (int off = 32; off > 0; off >>= 1) {
        s  += __shfl_down(s, off, 64);
        s2 += __shfl_down(s2, off, 64);
    }
    __shared__ float ps[8], ps2[8];
    int wave = threadIdx.x >> 6, lane = threadIdx.x & 63;
    if (lane == 0) { ps[wave] = s; ps2[wave] = s2; }
    __syncthreads();
    float mu = 0.f, m2 = 0.f;
    #pragma unroll
    for (int i = 0; i < 8; i++) { mu += ps[i]; m2 += ps2[i]; }
    mu *= (1.0f / 512.0f); m2 *= (1.0f / 512.0f);
    float rs = rsqrtf(m2 - mu * mu + 1e-5f);
    float y = (v - mu) * rs * g[c] + bta[c];
    xln[(size_t)token * 512 + c] = f2bf(y);
}

// ---------------------------------------------------------------------------
// LN2 over f32 input -> bf16
__global__ __launch_bounds__(512) void ln2_kernel(const float* __restrict__ xin,
        const float* __restrict__ g, const float* __restrict__ bta,
        ushort* __restrict__ out) {
    int token = blockIdx.x;
    int c = threadIdx.x;
    float v = xin[(size_t)token * 512 + c];
    float s = v, s2 = v * v;
    #pragma unroll
    for (int off = 32; off > 0; off >>= 1) {
        s  += __shfl_down(s, off, 64);
        s2 += __shfl_down(s2, off, 64);
    }
    __shared__ float ps[8], ps2[8];
    int wave = threadIdx.x >> 6, lane = threadIdx.x & 63;
    if (lane == 0) { ps[wave] = s; ps2[wave] = s2; }
    __syncthreads();
    float mu = 0.f, m2 = 0.f;
    #pragma unroll
    for (int i = 0; i < 8; i++) { mu += ps[i]; m2 += ps2[i]; }
    mu *= (1.0f / 512.0f); m2 *= (1.0f / 512.0f);
    float rs = rsqrtf(m2 - mu * mu + 1e-5f);
    float y = (v - mu) * rs * g[c] + bta[c];
    out[(size_t)token * 512 + c] = f2bf(y);
}

// ---------------------------------------------------------------------------
// Generic MFMA GEMM: C = A[MxK](bf16) @ B[KxN](f32 weights) + bias(f32).
// 64x64 block tile, BK=32, 256 threads (4 waves, each 16 rows x 64 cols).
#define EPI_BF16   0
#define EPI_F32RES 1
#define EPI_GELU   2

template<int EPI>
__global__ __launch_bounds__(256) void gemm_kernel(
        const ushort* __restrict__ A, const float* __restrict__ Bw,
        const float* __restrict__ bias, const float* __restrict__ resid,
        float* __restrict__ outF, ushort* __restrict__ outB,
        int M, int N, int K) {
    __shared__ __align__(16) ushort As[64][40];   // [m][k], stride 40 shorts = 80B
    __shared__ __align__(16) ushort Bs[64][40];   // transposed: [n][k]
    int tid = threadIdx.x;
    int wave = tid >> 6, lane = tid & 63;
    int l16 = lane & 15, quad = lane >> 4;
    int m0 = blockIdx.y * 64, n0 = blockIdx.x * 64;
    int am = tid >> 2, ak = (tid & 3) * 8;        // A staging: 16B per thread
    int bn = tid & 63, bk = (tid >> 6) * 8;       // B staging: 8-element k strip
    f32x4 acc[4] = {};
    for (int k0 = 0; k0 < K; k0 += 32) {
        *(short8*)&As[am][ak] = *(const short8*)(A + (size_t)(m0 + am) * K + k0 + ak);
        short8 bv;
        #pragma unroll
        for (int i = 0; i < 8; i++)
            bv[i] = (short)f2bf(Bw[(size_t)(k0 + bk + i) * N + n0 + bn]);
        *(short8*)&Bs[bn][bk] = bv;
        __syncthreads();
        short8 af = *(short8*)&As[wave * 16 + l16][quad * 8];
        #pragma unroll
        for (int s = 0; s < 4; s++) {
            short8 bf = *(short8*)&Bs[s * 16 + l16][quad * 8];
            acc[s] = __builtin_amdgcn_mfma_f32_16x16x32_bf16(af, bf, acc[s], 0, 0, 0);
        }
        __syncthreads();
    }
    int row_base = m0 + wave * 16 + quad * 4;
    #pragma unroll
    for (int s = 0; s < 4; s++) {
        int col = n0 + s * 16 + l16;
        float bvf = bias[col];
        #pragma unroll
        for (int r = 0; r < 4; r++) {
            int row = row_base + r;
            float v = acc[s][r] + bvf;
            if constexpr (EPI == EPI_F32RES) {
                outF[(size_t)row * N + col] = v + resid[(size_t)row * N + col];
            } else if constexpr (EPI == EPI_GELU) {
                float gg = 0.5f * v * (1.0f + erff(v * 0.70710678118654752f));
                outB[(size_t)row * N + col] = f2bf(gg);
            } else {
                outB[(size_t)row * N + col] = f2bf(v);
            }
        }
    }
}

// ---------------------------------------------------------------------------
// Flash attention, split-K in block: one block per (b, h, 64 q-rows), 512 threads
// = 8 waves. Waves 0-3 process keys [0,1024) for q-row groups 0..3; waves 4-7
// process keys [1024,2048) for the same q-row groups. Partial (m, l, accO)
// merged through LDS at the end. Doubles waves/CU (8 -> 16) for latency hiding.
// qkv layout (internal bf16): [token][1536], q|k|v at h*64, 512+h*64, 1024+h*64.
__global__ __launch_bounds__(512) void flash_kernel(const ushort* __restrict__ qkv,
        ushort* __restrict__ o) {
    __shared__ __align__(16) char smem[36864];
    auto Vt   = (ushort (*)[64][72])smem;             // Vt[half][d][key], 18432 B
    auto Pt   = (ushort (*)[16][72])(smem + 18432);   // Pt[wave][q][key], 18432 B
    auto cbuf = (float (*)[24][64])smem;              // combine buffer (aliased)

    int tid = threadIdx.x;
    int wave = tid >> 6, lane = tid & 63;
    int kh = wave >> 2;          // which key half this wave owns
    int wq = wave & 3;           // which 16-q-row group
    int l16 = lane & 15, quad = lane >> 4;
    int bidx = blockIdx.x;
    int qt = bidx & 31;
    int h = (bidx >> 5) & 7;
    int b = bidx >> 8;
    int q0 = qt * 64;
    const size_t base = (size_t)b * 2048 * 1536;

    short8 aq[2];
    {
        int qrow = q0 + wq * 16 + l16;
        const ushort* qp = qkv + base + (size_t)qrow * 1536 + h * 64;
        aq[0] = *(const short8*)(qp + quad * 8);
        aq[1] = *(const short8*)(qp + 32 + quad * 8);
    }
    f32x4 accO[4] = {};
    float mrow[4] = {-INFINITY, -INFINITY, -INFINITY, -INFINITY};
    float lrow[4] = {0.f, 0.f, 0.f, 0.f};
    int htid = tid & 255;                 // thread id within the half (4 waves)
    int vkey = htid & 63, vdb = (htid >> 6) * 16;

    for (int it = 0; it < 16; ++it) {
        int kb = kh * 1024 + it * 64;
        // V tile -> registers early; latency hides under QK^T + softmax (T14)
        const ushort* vp = qkv + base + (size_t)(kb + vkey) * 1536 + 1024 + h * 64 + vdb;
        short8 v0 = *(const short8*)vp;
        short8 v1 = *(const short8*)(vp + 8);
        // S = Q K^T : B-frag straight from global (contiguous d-runs of K rows)
        f32x4 sacc[4] = {};
        __builtin_amdgcn_s_setprio(1);
        #pragma unroll
        for (int c = 0; c < 2; c++) {
            #pragma unroll
            for (int s = 0; s < 4; s++) {
                const ushort* kp = qkv + base + (size_t)(kb + s * 16 + l16) * 1536
                                   + 512 + h * 64 + c * 32 + quad * 8;
                short8 kf = *(const short8*)kp;
                sacc[s] = __builtin_amdgcn_mfma_f32_16x16x32_bf16(aq[c], kf, sacc[s], 0, 0, 0);
            }
        }
        __builtin_amdgcn_s_setprio(0);
        // online softmax per q-row (rows quad*4+r, cols s*16+l16)
        float p[4][4];
        #pragma unroll
        for (int r = 0; r < 4; r++) {
            float tm = fmaxf(fmaxf(sacc[0][r], sacc[1][r]), fmaxf(sacc[2][r], sacc[3][r]));
            #pragma unroll
            for (int off = 1; off < 16; off <<= 1)
                tm = fmaxf(tm, __shfl_xor(tm, off, 16));
            float mn = fmaxf(mrow[r], tm * 0.125f);
            float al = __expf(mrow[r] - mn);
            float rsum = 0.f;
            #pragma unroll
            for (int s = 0; s < 4; s++) {
                float pv = __expf(sacc[s][r] * 0.125f - mn);
                p[s][r] = pv;
                rsum += pv;
            }
            #pragma unroll
            for (int off = 1; off < 16; off <<= 1)
                rsum += __shfl_xor(rsum, off, 16);
            lrow[r] = lrow[r] * al + rsum;
            mrow[r] = mn;
            #pragma unroll
            for (int s = 0; s < 4; s++) accO[s][r] *= al;
        }
        __syncthreads();   // previous iteration's Vt/Pt readers done
        // stage V (regs already in flight) and P
        #pragma unroll
        for (int i = 0; i < 8; i++) Vt[kh][vdb + i][vkey] = (ushort)v0[i];
        #pragma unroll
        for (int i = 0; i < 8; i++) Vt[kh][vdb + 8 + i][vkey] = (ushort)v1[i];
        #pragma unroll
        for (int s = 0; s < 4; s++)
            #pragma unroll
            for (int r = 0; r < 4; r++)
                Pt[wave][quad * 4 + r][s * 16 + l16] = f2bf(p[s][r]);
        __syncthreads();   // staged & visible
        // O += P @ V
        __builtin_amdgcn_s_setprio(1);
        #pragma unroll
        for (int ks = 0; ks < 2; ks++) {
            short8 ap = *(short8*)&Pt[wave][l16][ks * 32 + quad * 8];
            #pragma unroll
            for (int s = 0; s < 4; s++) {
                short8 vf = *(short8*)&Vt[kh][s * 16 + l16][ks * 32 + quad * 8];
                accO[s] = __builtin_amdgcn_mfma_f32_16x16x32_bf16(ap, vf, accO[s], 0, 0, 0);
            }
        }
        __builtin_amdgcn_s_setprio(0);
    }
    // ---- merge the two key-half partials (wave w with wave w+4) ----
    __syncthreads();                       // all Vt/Pt reads done; safe to alias
    if (kh == 1) {
        #pragma unroll
        for (int r = 0; r < 4; r++) {
            cbuf[wq][r][lane]     = mrow[r];
            cbuf[wq][4 + r][lane] = lrow[r];
        }
        #pragma unroll
        for (int s = 0; s < 4; s++)
            #pragma unroll
            for (int r = 0; r < 4; r++)
                cbuf[wq][8 + s * 4 + r][lane] = accO[s][r];
    }
    __syncthreads();
    if (kh == 0) {
        #pragma unroll
        for (int r = 0; r < 4; r++) {
            float m1 = cbuf[wq][r][lane];
            float l1 = cbuf[wq][4 + r][lane];
            float mn = fmaxf(mrow[r], m1);
            float a0 = __expf(mrow[r] - mn);
            float a1 = __expf(m1 - mn);
            float rl = 1.0f / (lrow[r] * a0 + l1 * a1);
            int qrow = q0 + wq * 16 + quad * 4 + r;
            #pragma unroll
            for (int s = 0; s < 4; s++) {
                float ov = (accO[s][r] * a0 + cbuf[wq][8 + s * 4 + r][lane] * a1) * rl;
                o[((size_t)(b * 2048 + qrow)) * 512 + h * 64 + s * 16 + l16] = f2bf(ov);
            }
        }
    }
}

// ---------------------------------------------------------------------------
// Output transpose: x3[token][c] f32 -> out[b,t,c,l] f32, LDS tiled 32x32
__global__ __launch_bounds__(256) void tout_kernel(const float* __restrict__ x3,
        float* __restrict__ out) {
    __shared__ float tile[32][33];
    int bt = blockIdx.z;            // 0..15  (b*8+t)
    int l0 = blockIdx.y * 32;       // 0..255
    int c0 = blockIdx.x * 32;       // 0..511
    int tx = threadIdx.x, ty = threadIdx.y;   // 32 x 8
    #pragma unroll
    for (int i = 0; i < 4; i++) {
        int l = ty + i * 8;
        tile[l][tx] = x3[((size_t)bt * 256 + l0 + l) * 512 + c0 + tx];
    }
    __syncthreads();
    #pragma unroll
    for (int i = 0; i < 4; i++) {
        int cc = ty + i * 8;
        out[((size_t)bt * 512 + c0 + cc) * 256 + l0 + tx] = tile[tx][cc];
    }
}

// ---------------------------------------------------------------------------
extern "C" void kernel_launch(void* const* d_in, const int* in_sizes, int n_in,
                              void* d_out, int out_size, void* d_ws, size_t ws_size,
                              hipStream_t stream) {
    const float* in_feat = (const float*)d_in[0];
    const float* qkv_w  = (const float*)d_in[1];
    const float* qkv_b  = (const float*)d_in[2];
    const float* proj_w = (const float*)d_in[3];
    const float* proj_b = (const float*)d_in[4];
    const float* ln1_g  = (const float*)d_in[5];
    const float* ln1_b  = (const float*)d_in[6];
    const float* w1     = (const float*)d_in[7];
    const float* b1     = (const float*)d_in[8];
    const float* w2     = (const float*)d_in[9];
    const float* b2     = (const float*)d_in[10];
    const float* ln2_g  = (const float*)d_in[11];
    const float* ln2_b  = (const float*)d_in[12];

    char* ws = (char*)d_ws;
    float*  x    = (float*) (ws);              // 8 MB residual 1 (reused for final x3)
    float*  x2   = (float*) (ws + 8388608);    // 8 MB residual 2
    ushort* xln  = (ushort*)(ws + 16777216);   // 4 MB LN1 out (bf16)
    ushort* h2   = (ushort*)(ws + 20971520);   // 4 MB LN2 out (bf16)
    ushort* ao   = (ushort*)(ws + 25165824);   // 4 MB attention out (bf16)
    ushort* qkv  = (ushort*)(ws + 29360128);   // 12 MB qkv (bf16)
    ushort* gbuf = (ushort*)(ws + 41943040);   // 16 MB MLP hidden (bf16)

    // 1) transpose + LN1
    prep_kernel<<<4096, 512, 0, stream>>>(in_feat, ln1_g, ln1_b, x, xln);
    // 2) QKV: [4096,512] @ [512,1536] + b -> bf16
    gemm_kernel<EPI_BF16><<<dim3(24, 64), 256, 0, stream>>>(
        xln, qkv_w, qkv_b, nullptr, nullptr, qkv, 4096, 1536, 512);
    // 3) attention (512 blocks x 512 threads, in-block key-split)
    flash_kernel<<<512, 512, 0, stream>>>(qkv, ao);
    // 4) proj + residual -> f32 x2
    gemm_kernel<EPI_F32RES><<<dim3(8, 64), 256, 0, stream>>>(
        ao, proj_w, proj_b, x, x2, nullptr, 4096, 512, 512);
    // 5) LN2
    ln2_kernel<<<4096, 512, 0, stream>>>(x2, ln2_g, ln2_b, h2);
    // 6) MLP up + GELU -> bf16
    gemm_kernel<EPI_GELU><<<dim3(32, 64), 256, 0, stream>>>(
        h2, w1, b1, nullptr, nullptr, gbuf, 4096, 2048, 512);
    // 7) MLP down + residual -> f32 (into x buffer)
    gemm_kernel<EPI_F32RES><<<dim3(8, 64), 256, 0, stream>>>(
        gbuf, w2, b2, x2, x, nullptr, 4096, 512, 2048);
    // 8) output transpose -> f32 out
    tout_kernel<<<dim3(16, 8, 16), dim3(32, 8), 0, stream>>>(x, (float*)d_out);
}

// Round 2
// 275.851 us; speedup vs baseline: 1.1927x; 1.1662x over previous
//
#include <hip/hip_runtime.h>
#include <stdint.h>
#include <math.h>

typedef __attribute__((ext_vector_type(8))) short short8;
typedef __attribute__((ext_vector_type(4))) float f32x4;

__device__ __forceinline__ ushort f2bf(float f) {
    union { float f; uint32_t i; } v; v.f = f;
    uint32_t r = v.i + 0x7FFFu + ((v.i >> 16) & 1u);
    return (ushort)(r >> 16);
}
__device__ __forceinline__ float bf2f(ushort u) {
    union { uint32_t i; float f; } v; v.i = ((uint32_t)u) << 16; return v.f;
}

// ---------------------------------------------------------------------------
// Kernel 1: input transpose [B,T,C,L] (f32) -> x[token][c] (f32) + LN1 -> xln (bf16)
// one block per token (4096 blocks x 512 threads)
__global__ __launch_bounds__(512) void prep_kernel(const float* __restrict__ in,
        const float* __restrict__ g, const float* __restrict__ bta,
        float* __restrict__ x, ushort* __restrict__ xln) {
    int token = blockIdx.x;          // 0..4095
    int c = threadIdx.x;             // 0..511
    int b = token >> 11;
    int n = token & 2047;
    int t = n >> 8;
    int l = n & 255;
    size_t iidx = (((size_t)((b * 8 + t) * 512 + c)) << 8) + l;
    float v = in[iidx];
    x[(size_t)token * 512 + c] = v;

    float s = v, s2 = v * v;
    #pragma unroll
    for (int off = 32; off > 0; off >>= 1) {
        s  += __shfl_down(s, off, 64);
        s2 += __shfl_down(s2, off, 64);
    }
    __shared__ float ps[8], ps2[8];
    int wave = threadIdx.x >> 6, lane = threadIdx.x & 63;
    if (lane == 0) { ps[wave] = s; ps2[wave] = s2; }
    __syncthreads();
    float mu = 0.f, m2 = 0.f;
    #pragma unroll
    for (int i = 0; i < 8; i++) { mu += ps[i]; m2 += ps2[i]; }
    mu *= (1.0f / 512.0f); m2 *= (1.0f / 512.0f);
    float rs = rsqrtf(m2 - mu * mu + 1e-5f);
    float y = (v - mu) * rs * g[c] + bta[c];
    xln[(size_t)token * 512 + c] = f2bf(y);
}

// ---------------------------------------------------------------------------
// LN2 over f32 input -> bf16
__global__ __launch_bounds__(512) void ln2_kernel(const float* __restrict__ xin,
        const float* __restrict__ g, const float* __restrict__ bta,
        ushort* __restrict__ out) {
    int token = blockIdx.x;
    int c = threadIdx.x;
    float v = xin[(size_t)token * 512 + c];
    float s = v, s2 = v * v;
    #pragma unroll
    for (int off = 32; off > 0; off >>= 1) {
        s  += __shfl_down(s, off, 64);
        s2 += __shfl_down(s2, off, 64);
    }
    __shared__ float ps[8], ps2[8];
    int wave = threadIdx.x >> 6, lane = threadIdx.x & 63;
    if (lane == 0) { ps[wave] = s; ps2[wave] = s2; }
    __syncthreads();
    float mu = 0.f, m2 = 0.f;
    #pragma unroll
    for (int i = 0; i < 8; i++) { mu += ps[i]; m2 += ps2[i]; }
    mu *= (1.0f / 512.0f); m2 *= (1.0f / 512.0f);
    float rs = rsqrtf(m2 - mu * mu + 1e-5f);
    float y = (v - mu) * rs * g[c] + bta[c];
    out[(size_t)token * 512 + c] = f2bf(y);
}

// ---------------------------------------------------------------------------
// Generic MFMA GEMM: C = A[MxK](bf16) @ B[KxN](f32 weights) + bias(f32).
// 64x64 block tile, BK=32, 256 threads (4 waves, each 16 rows x 64 cols).
#define EPI_BF16   0
#define EPI_F32RES 1
#define EPI_GELU   2

template<int EPI>
__global__ __launch_bounds__(256) void gemm_kernel(
        const ushort* __restrict__ A, const float* __restrict__ Bw,
        const float* __restrict__ bias, const float* __restrict__ resid,
        float* __restrict__ outF, ushort* __restrict__ outB,
        int M, int N, int K) {
    __shared__ __align__(16) ushort As[64][40];   // [m][k], stride 40 shorts = 80B
    __shared__ __align__(16) ushort Bs[64][40];   // transposed: [n][k]
    int tid = threadIdx.x;
    int wave = tid >> 6, lane = tid & 63;
    int l16 = lane & 15, quad = lane >> 4;
    int m0 = blockIdx.y * 64, n0 = blockIdx.x * 64;
    int am = tid >> 2, ak = (tid & 3) * 8;        // A staging: 16B per thread
    int bn = tid & 63, bk = (tid >> 6) * 8;       // B staging: 8-element k strip
    f32x4 acc[4] = {};
    for (int k0 = 0; k0 < K; k0 += 32) {
        *(short8*)&As[am][ak] = *(const short8*)(A + (size_t)(m0 + am) * K + k0 + ak);
        short8 bv;
        #pragma unroll
        for (int i = 0; i < 8; i++)
            bv[i] = (short)f2bf(Bw[(size_t)(k0 + bk + i) * N + n0 + bn]);
        *(short8*)&Bs[bn][bk] = bv;
        __syncthreads();
        short8 af = *(short8*)&As[wave * 16 + l16][quad * 8];
        #pragma unroll
        for (int s = 0; s < 4; s++) {
            short8 bf = *(short8*)&Bs[s * 16 + l16][quad * 8];
            acc[s] = __builtin_amdgcn_mfma_f32_16x16x32_bf16(af, bf, acc[s], 0, 0, 0);
        }
        __syncthreads();
    }
    int row_base = m0 + wave * 16 + quad * 4;
    #pragma unroll
    for (int s = 0; s < 4; s++) {
        int col = n0 + s * 16 + l16;
        float bvf = bias[col];
        #pragma unroll
        for (int r = 0; r < 4; r++) {
            int row = row_base + r;
            float v = acc[s][r] + bvf;
            if constexpr (EPI == EPI_F32RES) {
                outF[(size_t)row * N + col] = v + resid[(size_t)row * N + col];
            } else if constexpr (EPI == EPI_GELU) {
                float gg = 0.5f * v * (1.0f + erff(v * 0.70710678118654752f));
                outB[(size_t)row * N + col] = f2bf(gg);
            } else {
                outB[(size_t)row * N + col] = f2bf(v);
            }
        }
    }
}

// ---------------------------------------------------------------------------
// Flash attention, split-K in block: one block per (b, h, 64 q-rows), 512 threads
// = 8 waves. Waves 0-3 own keys [0,1024), waves 4-7 own keys [1024,2048).
// K and V tiles are staged in LDS with COALESCED global loads (16 rows/instr,
// ~16 cache lines/instr) and software-pipelined (regs loaded for tile i+1 while
// tile i computes) -- the previous version issued per-lane row-divergent loads
// (64 lines/instr) from every wave, saturating the per-CU TA/L1 address path.
// qkv layout (internal bf16): [token][1536], q|k|v at h*64, 512+h*64, 1024+h*64.
__global__ __launch_bounds__(512) void flash_kernel(const ushort* __restrict__ qkv,
        ushort* __restrict__ o) {
    __shared__ __align__(16) char smem[55424];
    auto Ks  = (ushort (*)[64][72])smem;              // [kh][key][d]   18432 B
    auto Vt  = (ushort (*)[4640])(smem + 18432);      // [kh][VT(d,key)] 18560 B
    auto Pt  = (ushort (*)[16][72])(smem + 36992);    // [wave][q][key] 18432 B
    auto cbuf = (float (*)[24][64])smem;              // combine buffer (aliased)
    // VT(d,key) = d*72 + (d>>4)*8 + key  -- per-row offset breaks the d-group
    // (rows 16 apart == 0 mod 128B) bank conflict on transpose writes; reads
    // stay b128/16B-aligned since the offset is a multiple of 8 shorts.

    int tid = threadIdx.x;
    int wave = tid >> 6, lane = tid & 63;
    int kh = wave >> 2;          // which key half this wave owns
    int wq = wave & 3;           // which 16-q-row group
    int l16 = lane & 15, quad = lane >> 4;
    int bidx = blockIdx.x;
    int qt = bidx & 31;
    int h = (bidx >> 5) & 7;
    int b = bidx >> 8;
    int q0 = qt * 64;
    const size_t base = (size_t)b * 2048 * 1536;

    // staging assignment: per half (256 threads), thread -> (key row, 32B d-chunk)
    int htid = tid & 255;
    int srow = htid >> 2;            // key row 0..63
    int sg   = htid & 3;             // d-chunk 0..3
    int sdb  = sg * 16;              // d base (shorts)
    const ushort* kgbase = qkv + base + 512  + h * 64 + sdb;
    const ushort* vgbase = qkv + base + 1024 + h * 64 + sdb;
    int vldsoff = sdb * 72 + sg * 8 + srow;   // VT(sdb+0, srow); d>>4 == sg

    short8 aq[2];
    {
        int qrow = q0 + wq * 16 + l16;
        const ushort* qp = qkv + base + (size_t)qrow * 1536 + h * 64;
        aq[0] = *(const short8*)(qp + quad * 8);
        aq[1] = *(const short8*)(qp + 32 + quad * 8);
    }
    f32x4 accO[4] = {};
    float mrow[4] = {-INFINITY, -INFINITY, -INFINITY, -INFINITY};
    float lrow[4] = {0.f, 0.f, 0.f, 0.f};

    // prologue: stage tile 0
    {
        int kb = kh * 1024;
        const ushort* kp = kgbase + (size_t)(kb + srow) * 1536;
        short8 k0 = *(const short8*)kp;
        short8 k1 = *(const short8*)(kp + 8);
        const ushort* vp = vgbase + (size_t)(kb + srow) * 1536;
        short8 v0 = *(const short8*)vp;
        short8 v1 = *(const short8*)(vp + 8);
        *(short8*)&Ks[kh][srow][sdb]     = k0;
        *(short8*)&Ks[kh][srow][sdb + 8] = k1;
        #pragma unroll
        for (int i = 0; i < 8; i++) Vt[kh][vldsoff + i * 72] = (ushort)v0[i];
        #pragma unroll
        for (int i = 0; i < 8; i++) Vt[kh][vldsoff + (8 + i) * 72] = (ushort)v1[i];
    }
    __syncthreads();

    for (int it = 0; it < 16; ++it) {
        // 1) issue next tile's global loads -> regs (latency hides under compute)
        short8 nk0, nk1, nv0, nv1;
        bool pre = (it < 15);
        if (pre) {
            int kb = kh * 1024 + (it + 1) * 64;
            const ushort* kp = kgbase + (size_t)(kb + srow) * 1536;
            nk0 = *(const short8*)kp;
            nk1 = *(const short8*)(kp + 8);
            const ushort* vp = vgbase + (size_t)(kb + srow) * 1536;
            nv0 = *(const short8*)vp;
            nv1 = *(const short8*)(vp + 8);
        }
        // 2) S = Q K^T from LDS-staged K
        f32x4 sacc[4] = {};
        __builtin_amdgcn_s_setprio(1);
        #pragma unroll
        for (int c = 0; c < 2; c++) {
            #pragma unroll
            for (int s = 0; s < 4; s++) {
                short8 kf = *(short8*)&Ks[kh][s * 16 + l16][c * 32 + quad * 8];
                sacc[s] = __builtin_amdgcn_mfma_f32_16x16x32_bf16(aq[c], kf, sacc[s], 0, 0, 0);
            }
        }
        __builtin_amdgcn_s_setprio(0);
        // 3) online softmax per q-row (rows quad*4+r, cols s*16+l16)
        float p[4][4];
        #pragma unroll
        for (int r = 0; r < 4; r++) {
            float tm = fmaxf(fmaxf(sacc[0][r], sacc[1][r]), fmaxf(sacc[2][r], sacc[3][r]));
            #pragma unroll
            for (int off = 1; off < 16; off <<= 1)
                tm = fmaxf(tm, __shfl_xor(tm, off, 16));
            float mn = fmaxf(mrow[r], tm * 0.125f);
            float al = __expf(mrow[r] - mn);
            float rsum = 0.f;
            #pragma unroll
            for (int s = 0; s < 4; s++) {
                float pv = __expf(sacc[s][r] * 0.125f - mn);
                p[s][r] = pv;
                rsum += pv;
            }
            #pragma unroll
            for (int off = 1; off < 16; off <<= 1)
                rsum += __shfl_xor(rsum, off, 16);
            lrow[r] = lrow[r] * al + rsum;
            mrow[r] = mn;
            #pragma unroll
            for (int s = 0; s < 4; s++) accO[s][r] *= al;
        }
        // 4) P -> Pt (per-wave private buffer, no cross-wave hazard)
        #pragma unroll
        for (int s = 0; s < 4; s++)
            #pragma unroll
            for (int r = 0; r < 4; r++)
                Pt[wave][quad * 4 + r][s * 16 + l16] = f2bf(p[s][r]);
        // 5) O += P @ V (reads Vt tile it)
        __builtin_amdgcn_s_setprio(1);
        #pragma unroll
        for (int ks = 0; ks < 2; ks++) {
            short8 ap = *(short8*)&Pt[wave][l16][ks * 32 + quad * 8];
            #pragma unroll
            for (int s = 0; s < 4; s++) {
                short8 vf = *(short8*)&Vt[kh][(s * 16 + l16) * 72 + s * 8 + ks * 32 + quad * 8];
                accO[s] = __builtin_amdgcn_mfma_f32_16x16x32_bf16(ap, vf, accO[s], 0, 0, 0);
            }
        }
        __builtin_amdgcn_s_setprio(0);
        __syncthreads();   // all waves done reading Ks/Vt tile it
        // 6) write prefetched tile it+1 to LDS
        if (pre) {
            *(short8*)&Ks[kh][srow][sdb]     = nk0;
            *(short8*)&Ks[kh][srow][sdb + 8] = nk1;
            #pragma unroll
            for (int i = 0; i < 8; i++) Vt[kh][vldsoff + i * 72] = (ushort)nv0[i];
            #pragma unroll
            for (int i = 0; i < 8; i++) Vt[kh][vldsoff + (8 + i) * 72] = (ushort)nv1[i];
        }
        __syncthreads();   // staged & visible
    }
    // ---- merge the two key-half partials (wave w with wave w+4) ----
    if (kh == 1) {
        #pragma unroll
        for (int r = 0; r < 4; r++) {
            cbuf[wq][r][lane]     = mrow[r];
            cbuf[wq][4 + r][lane] = lrow[r];
        }
        #pragma unroll
        for (int s = 0; s < 4; s++)
            #pragma unroll
            for (int r = 0; r < 4; r++)
                cbuf[wq][8 + s * 4 + r][lane] = accO[s][r];
    }
    __syncthreads();
    if (kh == 0) {
        #pragma unroll
        for (int r = 0; r < 4; r++) {
            float m1 = cbuf[wq][r][lane];
            float l1 = cbuf[wq][4 + r][lane];
            float mn = fmaxf(mrow[r], m1);
            float a0 = __expf(mrow[r] - mn);
            float a1 = __expf(m1 - mn);
            float rl = 1.0f / (lrow[r] * a0 + l1 * a1);
            int qrow = q0 + wq * 16 + quad * 4 + r;
            #pragma unroll
            for (int s = 0; s < 4; s++) {
                float ov = (accO[s][r] * a0 + cbuf[wq][8 + s * 4 + r][lane] * a1) * rl;
                o[((size_t)(b * 2048 + qrow)) * 512 + h * 64 + s * 16 + l16] = f2bf(ov);
            }
        }
    }
}

// ---------------------------------------------------------------------------
// Output transpose: x3[token][c] f32 -> out[b,t,c,l] f32, LDS tiled 32x32
__global__ __launch_bounds__(256) void tout_kernel(const float* __restrict__ x3,
        float* __restrict__ out) {
    __shared__ float tile[32][33];
    int bt = blockIdx.z;            // 0..15  (b*8+t)
    int l0 = blockIdx.y * 32;       // 0..255
    int c0 = blockIdx.x * 32;       // 0..511
    int tx = threadIdx.x, ty = threadIdx.y;   // 32 x 8
    #pragma unroll
    for (int i = 0; i < 4; i++) {
        int l = ty + i * 8;
        tile[l][tx] = x3[((size_t)bt * 256 + l0 + l) * 512 + c0 + tx];
    }
    __syncthreads();
    #pragma unroll
    for (int i = 0; i < 4; i++) {
        int cc = ty + i * 8;
        out[((size_t)bt * 512 + c0 + cc) * 256 + l0 + tx] = tile[tx][cc];
    }
}

// ---------------------------------------------------------------------------
extern "C" void kernel_launch(void* const* d_in, const int* in_sizes, int n_in,
                              void* d_out, int out_size, void* d_ws, size_t ws_size,
                              hipStream_t stream) {
    const float* in_feat = (const float*)d_in[0];
    const float* qkv_w  = (const float*)d_in[1];
    const float* qkv_b  = (const float*)d_in[2];
    const float* proj_w = (const float*)d_in[3];
    const float* proj_b = (const float*)d_in[4];
    const float* ln1_g  = (const float*)d_in[5];
    const float* ln1_b  = (const float*)d_in[6];
    const float* w1     = (const float*)d_in[7];
    const float* b1     = (const float*)d_in[8];
    const float* w2     = (const float*)d_in[9];
    const float* b2     = (const float*)d_in[10];
    const float* ln2_g  = (const float*)d_in[11];
    const float* ln2_b  = (const float*)d_in[12];

    char* ws = (char*)d_ws;
    float*  x    = (float*) (ws);              // 8 MB residual 1 (reused for final x3)
    float*  x2   = (float*) (ws + 8388608);    // 8 MB residual 2
    ushort* xln  = (ushort*)(ws + 16777216);   // 4 MB LN1 out (bf16)
    ushort* h2   = (ushort*)(ws + 20971520);   // 4 MB LN2 out (bf16)
    ushort* ao   = (ushort*)(ws + 25165824);   // 4 MB attention out (bf16)
    ushort* qkv  = (ushort*)(ws + 29360128);   // 12 MB qkv (bf16)
    ushort* gbuf = (ushort*)(ws + 41943040);   // 16 MB MLP hidden (bf16)

    // 1) transpose + LN1
    prep_kernel<<<4096, 512, 0, stream>>>(in_feat, ln1_g, ln1_b, x, xln);
    // 2) QKV: [4096,512] @ [512,1536] + b -> bf16
    gemm_kernel<EPI_BF16><<<dim3(24, 64), 256, 0, stream>>>(
        xln, qkv_w, qkv_b, nullptr, nullptr, qkv, 4096, 1536, 512);
    // 3) attention (512 blocks x 512 threads, in-block key-split)
    flash_kernel<<<512, 512, 0, stream>>>(qkv, ao);
    // 4) proj + residual -> f32 x2
    gemm_kernel<EPI_F32RES><<<dim3(8, 64), 256, 0, stream>>>(
        ao, proj_w, proj_b, x, x2, nullptr, 4096, 512, 512);
    // 5) LN2
    ln2_kernel<<<4096, 512, 0, stream>>>(x2, ln2_g, ln2_b, h2);
    // 6) MLP up + GELU -> bf16
    gemm_kernel<EPI_GELU><<<dim3(32, 64), 256, 0, stream>>>(
        h2, w1, b1, nullptr, nullptr, gbuf, 4096, 2048, 512);
    // 7) MLP down + residual -> f32 (into x buffer)
    gemm_kernel<EPI_F32RES><<<dim3(8, 64), 256, 0, stream>>>(
        gbuf, w2, b2, x2, x, nullptr, 4096, 512, 2048);
    // 8) output transpose -> f32 out
    tout_kernel<<<dim3(16, 8, 16), dim3(32, 8), 0, stream>>>(x, (float*)d_out);
}

// Round 3
// 254.221 us; speedup vs baseline: 1.2942x; 1.0851x over previous
//
#include <hip/hip_runtime.h>
#include <stdint.h>
#include <math.h>

typedef __attribute__((ext_vector_type(8))) short short8;
typedef __attribute__((ext_vector_type(4))) float f32x4;

__device__ __forceinline__ ushort f2bf(float f) {
    union { float f; uint32_t i; } v; v.f = f;
    uint32_t r = v.i + 0x7FFFu + ((v.i >> 16) & 1u);
    return (ushort)(r >> 16);
}
__device__ __forceinline__ float bf2f(ushort u) {
    union { uint32_t i; float f; } v; v.i = ((uint32_t)u) << 16; return v.f;
}

// async global->LDS, 16B per lane. LDS dest is wave-uniform base + lane*16.
__device__ __forceinline__ void gload_lds16(const ushort* gp, ushort* lp) {
    __builtin_amdgcn_global_load_lds(
        (const __attribute__((address_space(1))) void*)gp,
        (__attribute__((address_space(3))) void*)lp, 16, 0, 0);
}

// ---------------------------------------------------------------------------
// Kernel 1: input transpose [B,T,C,L] (f32) -> x[token][c] (f32) + LN1 -> xln (bf16)
// one block per token (4096 blocks x 512 threads)
__global__ __launch_bounds__(512) void prep_kernel(const float* __restrict__ in,
        const float* __restrict__ g, const float* __restrict__ bta,
        float* __restrict__ x, ushort* __restrict__ xln) {
    int token = blockIdx.x;          // 0..4095
    int c = threadIdx.x;             // 0..511
    int b = token >> 11;
    int n = token & 2047;
    int t = n >> 8;
    int l = n & 255;
    size_t iidx = (((size_t)((b * 8 + t) * 512 + c)) << 8) + l;
    float v = in[iidx];
    x[(size_t)token * 512 + c] = v;

    float s = v, s2 = v * v;
    #pragma unroll
    for (int off = 32; off > 0; off >>= 1) {
        s  += __shfl_down(s, off, 64);
        s2 += __shfl_down(s2, off, 64);
    }
    __shared__ float ps[8], ps2[8];
    int wave = threadIdx.x >> 6, lane = threadIdx.x & 63;
    if (lane == 0) { ps[wave] = s; ps2[wave] = s2; }
    __syncthreads();
    float mu = 0.f, m2 = 0.f;
    #pragma unroll
    for (int i = 0; i < 8; i++) { mu += ps[i]; m2 += ps2[i]; }
    mu *= (1.0f / 512.0f); m2 *= (1.0f / 512.0f);
    float rs = rsqrtf(m2 - mu * mu + 1e-5f);
    float y = (v - mu) * rs * g[c] + bta[c];
    xln[(size_t)token * 512 + c] = f2bf(y);
}

// ---------------------------------------------------------------------------
// LN2 over f32 input -> bf16
__global__ __launch_bounds__(512) void ln2_kernel(const float* __restrict__ xin,
        const float* __restrict__ g, const float* __restrict__ bta,
        ushort* __restrict__ out) {
    int token = blockIdx.x;
    int c = threadIdx.x;
    float v = xin[(size_t)token * 512 + c];
    float s = v, s2 = v * v;
    #pragma unroll
    for (int off = 32; off > 0; off >>= 1) {
        s  += __shfl_down(s, off, 64);
        s2 += __shfl_down(s2, off, 64);
    }
    __shared__ float ps[8], ps2[8];
    int wave = threadIdx.x >> 6, lane = threadIdx.x & 63;
    if (lane == 0) { ps[wave] = s; ps2[wave] = s2; }
    __syncthreads();
    float mu = 0.f, m2 = 0.f;
    #pragma unroll
    for (int i = 0; i < 8; i++) { mu += ps[i]; m2 += ps2[i]; }
    mu *= (1.0f / 512.0f); m2 *= (1.0f / 512.0f);
    float rs = rsqrtf(m2 - mu * mu + 1e-5f);
    float y = (v - mu) * rs * g[c] + bta[c];
    out[(size_t)token * 512 + c] = f2bf(y);
}

// ---------------------------------------------------------------------------
// Fused weight transpose+convert: Bw f32 [K][N] -> Bt bf16 [N][K], all four
// weights in one launch (block id range -> which weight). 32x32 LDS tiles.
__global__ __launch_bounds__(256) void wtrans_kernel(
        const float* __restrict__ wa, ushort* __restrict__ ta,
        const float* __restrict__ wb, ushort* __restrict__ tb,
        const float* __restrict__ wc, ushort* __restrict__ tc,
        const float* __restrict__ wd, ushort* __restrict__ td) {
    __shared__ float tile[32][33];
    int bid = blockIdx.x;
    const float* W; ushort* T; int K, N, tn, tk;
    if (bid < 768)       { W = wa; T = ta; K = 512;  N = 1536; tn = bid % 48; tk = bid / 48; }
    else if (bid < 1024) { bid -= 768;  W = wb; T = tb; K = 512;  N = 512;  tn = bid % 16; tk = bid / 16; }
    else if (bid < 2048) { bid -= 1024; W = wc; T = tc; K = 512;  N = 2048; tn = bid % 64; tk = bid / 64; }
    else                 { bid -= 2048; W = wd; T = td; K = 2048; N = 512;  tn = bid % 16; tk = bid / 16; }
    int n0 = tn * 32, k0 = tk * 32;
    int tx = threadIdx.x & 31, ty = threadIdx.x >> 5;   // 32 x 8
    #pragma unroll
    for (int i = 0; i < 4; i++)
        tile[ty + i * 8][tx] = W[(size_t)(k0 + ty + i * 8) * N + n0 + tx];
    __syncthreads();
    #pragma unroll
    for (int i = 0; i < 4; i++) {
        int nn = ty + i * 8;
        T[(size_t)(n0 + nn) * K + k0 + tx] = f2bf(tile[tx][nn]);
    }
}

// ---------------------------------------------------------------------------
// MFMA GEMM: C[M][N] = A[M][K](bf16) @ Bt[N][K](bf16, pre-transposed) + bias.
// 64x128 tile, BK=64, 256 threads = 4 waves, each wave computes 64x32
// (4x2 frags of 16x16x32). Staging via global_load_lds width-16 with
// XOR-swizzled SOURCE addresses (chunk c of row r -> slot c^(r&7)), so
// ds_read_b128 hits all 32 banks at 2 lanes/bank (free, m136).
#define EPI_BF16   0
#define EPI_F32RES 1
#define EPI_GELU   2

template<int EPI>
__global__ __launch_bounds__(256) void gemm_kernel(
        const ushort* __restrict__ A, const ushort* __restrict__ Bt,
        const float* __restrict__ bias, const float* __restrict__ resid,
        float* __restrict__ outF, ushort* __restrict__ outB,
        int M, int N, int K) {
    __shared__ __align__(16) ushort As[64 * 64];    // [row][64] linear, 8 KB
    __shared__ __align__(16) ushort Bs[128 * 64];   // [col][64] linear, 16 KB
    int tid = threadIdx.x;
    int wave = tid >> 6, lane = tid & 63;
    int l16 = lane & 15, quad = lane >> 4;
    int wc = wave;                       // wave's 32-col slice of the 128-col tile
    int m0 = blockIdx.y * 64, n0 = blockIdx.x * 128;

    f32x4 acc[4][2] = {};
    for (int k0 = 0; k0 < K; k0 += 64) {
        // stage A: 64 rows x 128B = 8KB = 512 chunks -> 2 calls
        #pragma unroll
        for (int c = 0; c < 2; c++) {
            int e = c * 256 + tid;
            int row = e >> 3, ch = e & 7;
            int sc = ch ^ (row & 7);     // pre-swizzled source -> swizzled LDS
            gload_lds16(A + (size_t)(m0 + row) * K + k0 + sc * 8,
                        As + (size_t)(c * 256 + wave * 64) * 8);
        }
        // stage B: 128 rows x 128B = 16KB -> 4 calls
        #pragma unroll
        for (int c = 0; c < 4; c++) {
            int e = c * 256 + tid;
            int row = e >> 3, ch = e & 7;
            int sc = ch ^ (row & 7);
            gload_lds16(Bt + (size_t)(n0 + row) * K + k0 + sc * 8,
                        Bs + (size_t)(c * 256 + wave * 64) * 8);
        }
        __syncthreads();   // vmcnt(0) drain: staged tile visible
        #pragma unroll
        for (int kk = 0; kk < 2; kk++) {
            short8 af[4], bf[2];
            #pragma unroll
            for (int i = 0; i < 4; i++) {
                int row = i * 16 + l16;
                af[i] = *(const short8*)&As[row * 64 + (((kk * 4 + quad) ^ (row & 7)) * 8)];
            }
            #pragma unroll
            for (int j = 0; j < 2; j++) {
                int row = wc * 32 + j * 16 + l16;
                bf[j] = *(const short8*)&Bs[row * 64 + (((kk * 4 + quad) ^ (row & 7)) * 8)];
            }
            #pragma unroll
            for (int i = 0; i < 4; i++)
                #pragma unroll
                for (int j = 0; j < 2; j++)
                    acc[i][j] = __builtin_amdgcn_mfma_f32_16x16x32_bf16(af[i], bf[j], acc[i][j], 0, 0, 0);
        }
        __syncthreads();   // tile consumed; safe to overwrite next iter
    }
    // epilogue: C frag layout col=l16, row=quad*4+r
    #pragma unroll
    for (int i = 0; i < 4; i++) {
        int row_base = m0 + i * 16 + quad * 4;
        #pragma unroll
        for (int j = 0; j < 2; j++) {
            int col = n0 + wc * 32 + j * 16 + l16;
            float bvf = bias[col];
            #pragma unroll
            for (int r = 0; r < 4; r++) {
                int row = row_base + r;
                float v = acc[i][j][r] + bvf;
                if constexpr (EPI == EPI_F32RES) {
                    outF[(size_t)row * N + col] = v + resid[(size_t)row * N + col];
                } else if constexpr (EPI == EPI_GELU) {
                    float gg = 0.5f * v * (1.0f + erff(v * 0.70710678118654752f));
                    outB[(size_t)row * N + col] = f2bf(gg);
                } else {
                    outB[(size_t)row * N + col] = f2bf(v);
                }
            }
        }
    }
}

// ---------------------------------------------------------------------------
// Flash attention, split-K in block: one block per (b, h, 64 q-rows), 512 threads
// = 8 waves. Waves 0-3 own keys [0,1024), waves 4-7 own keys [1024,2048).
// K and V tiles staged in LDS with coalesced global loads, software-pipelined.
// qkv layout (internal bf16): [token][1536], q|k|v at h*64, 512+h*64, 1024+h*64.
__global__ __launch_bounds__(512) void flash_kernel(const ushort* __restrict__ qkv,
        ushort* __restrict__ o) {
    __shared__ __align__(16) char smem[55424];
    auto Ks  = (ushort (*)[64][72])smem;              // [kh][key][d]   18432 B
    auto Vt  = (ushort (*)[4640])(smem + 18432);      // [kh][VT(d,key)] 18560 B
    auto Pt  = (ushort (*)[16][72])(smem + 36992);    // [wave][q][key] 18432 B
    auto cbuf = (float (*)[24][64])smem;              // combine buffer (aliased)
    // VT(d,key) = d*72 + (d>>4)*8 + key

    int tid = threadIdx.x;
    int wave = tid >> 6, lane = tid & 63;
    int kh = wave >> 2;          // which key half this wave owns
    int wq = wave & 3;           // which 16-q-row group
    int l16 = lane & 15, quad = lane >> 4;
    int bidx = blockIdx.x;
    int qt = bidx & 31;
    int h = (bidx >> 5) & 7;
    int b = bidx >> 8;
    int q0 = qt * 64;
    const size_t base = (size_t)b * 2048 * 1536;

    int htid = tid & 255;
    int srow = htid >> 2;            // key row 0..63
    int sg   = htid & 3;             // d-chunk 0..3
    int sdb  = sg * 16;              // d base (shorts)
    const ushort* kgbase = qkv + base + 512  + h * 64 + sdb;
    const ushort* vgbase = qkv + base + 1024 + h * 64 + sdb;
    int vldsoff = sdb * 72 + sg * 8 + srow;

    short8 aq[2];
    {
        int qrow = q0 + wq * 16 + l16;
        const ushort* qp = qkv + base + (size_t)qrow * 1536 + h * 64;
        aq[0] = *(const short8*)(qp + quad * 8);
        aq[1] = *(const short8*)(qp + 32 + quad * 8);
    }
    f32x4 accO[4] = {};
    float mrow[4] = {-INFINITY, -INFINITY, -INFINITY, -INFINITY};
    float lrow[4] = {0.f, 0.f, 0.f, 0.f};

    {   // prologue: stage tile 0
        int kb = kh * 1024;
        const ushort* kp = kgbase + (size_t)(kb + srow) * 1536;
        short8 k0 = *(const short8*)kp;
        short8 k1 = *(const short8*)(kp + 8);
        const ushort* vp = vgbase + (size_t)(kb + srow) * 1536;
        short8 v0 = *(const short8*)vp;
        short8 v1 = *(const short8*)(vp + 8);
        *(short8*)&Ks[kh][srow][sdb]     = k0;
        *(short8*)&Ks[kh][srow][sdb + 8] = k1;
        #pragma unroll
        for (int i = 0; i < 8; i++) Vt[kh][vldsoff + i * 72] = (ushort)v0[i];
        #pragma unroll
        for (int i = 0; i < 8; i++) Vt[kh][vldsoff + (8 + i) * 72] = (ushort)v1[i];
    }
    __syncthreads();

    for (int it = 0; it < 16; ++it) {
        short8 nk0, nk1, nv0, nv1;
        bool pre = (it < 15);
        if (pre) {
            int kb = kh * 1024 + (it + 1) * 64;
            const ushort* kp = kgbase + (size_t)(kb + srow) * 1536;
            nk0 = *(const short8*)kp;
            nk1 = *(const short8*)(kp + 8);
            const ushort* vp = vgbase + (size_t)(kb + srow) * 1536;
            nv0 = *(const short8*)vp;
            nv1 = *(const short8*)(vp + 8);
        }
        f32x4 sacc[4] = {};
        __builtin_amdgcn_s_setprio(1);
        #pragma unroll
        for (int c = 0; c < 2; c++) {
            #pragma unroll
            for (int s = 0; s < 4; s++) {
                short8 kf = *(short8*)&Ks[kh][s * 16 + l16][c * 32 + quad * 8];
                sacc[s] = __builtin_amdgcn_mfma_f32_16x16x32_bf16(aq[c], kf, sacc[s], 0, 0, 0);
            }
        }
        __builtin_amdgcn_s_setprio(0);
        float p[4][4];
        #pragma unroll
        for (int r = 0; r < 4; r++) {
            float tm = fmaxf(fmaxf(sacc[0][r], sacc[1][r]), fmaxf(sacc[2][r], sacc[3][r]));
            #pragma unroll
            for (int off = 1; off < 16; off <<= 1)
                tm = fmaxf(tm, __shfl_xor(tm, off, 16));
            float mn = fmaxf(mrow[r], tm * 0.125f);
            float al = __expf(mrow[r] - mn);
            float rsum = 0.f;
            #pragma unroll
            for (int s = 0; s < 4; s++) {
                float pv = __expf(sacc[s][r] * 0.125f - mn);
                p[s][r] = pv;
                rsum += pv;
            }
            #pragma unroll
            for (int off = 1; off < 16; off <<= 1)
                rsum += __shfl_xor(rsum, off, 16);
            lrow[r] = lrow[r] * al + rsum;
            mrow[r] = mn;
            #pragma unroll
            for (int s = 0; s < 4; s++) accO[s][r] *= al;
        }
        #pragma unroll
        for (int s = 0; s < 4; s++)
            #pragma unroll
            for (int r = 0; r < 4; r++)
                Pt[wave][quad * 4 + r][s * 16 + l16] = f2bf(p[s][r]);
        __builtin_amdgcn_s_setprio(1);
        #pragma unroll
        for (int ks = 0; ks < 2; ks++) {
            short8 ap = *(short8*)&Pt[wave][l16][ks * 32 + quad * 8];
            #pragma unroll
            for (int s = 0; s < 4; s++) {
                short8 vf = *(short8*)&Vt[kh][(s * 16 + l16) * 72 + s * 8 + ks * 32 + quad * 8];
                accO[s] = __builtin_amdgcn_mfma_f32_16x16x32_bf16(ap, vf, accO[s], 0, 0, 0);
            }
        }
        __builtin_amdgcn_s_setprio(0);
        __syncthreads();
        if (pre) {
            *(short8*)&Ks[kh][srow][sdb]     = nk0;
            *(short8*)&Ks[kh][srow][sdb + 8] = nk1;
            #pragma unroll
            for (int i = 0; i < 8; i++) Vt[kh][vldsoff + i * 72] = (ushort)nv0[i];
            #pragma unroll
            for (int i = 0; i < 8; i++) Vt[kh][vldsoff + (8 + i) * 72] = (ushort)nv1[i];
        }
        __syncthreads();
    }
    if (kh == 1) {
        #pragma unroll
        for (int r = 0; r < 4; r++) {
            cbuf[wq][r][lane]     = mrow[r];
            cbuf[wq][4 + r][lane] = lrow[r];
        }
        #pragma unroll
        for (int s = 0; s < 4; s++)
            #pragma unroll
            for (int r = 0; r < 4; r++)
                cbuf[wq][8 + s * 4 + r][lane] = accO[s][r];
    }
    __syncthreads();
    if (kh == 0) {
        #pragma unroll
        for (int r = 0; r < 4; r++) {
            float m1 = cbuf[wq][r][lane];
            float l1 = cbuf[wq][4 + r][lane];
            float mn = fmaxf(mrow[r], m1);
            float a0 = __expf(mrow[r] - mn);
            float a1 = __expf(m1 - mn);
            float rl = 1.0f / (lrow[r] * a0 + l1 * a1);
            int qrow = q0 + wq * 16 + quad * 4 + r;
            #pragma unroll
            for (int s = 0; s < 4; s++) {
                float ov = (accO[s][r] * a0 + cbuf[wq][8 + s * 4 + r][lane] * a1) * rl;
                o[((size_t)(b * 2048 + qrow)) * 512 + h * 64 + s * 16 + l16] = f2bf(ov);
            }
        }
    }
}

// ---------------------------------------------------------------------------
// Output transpose: x3[token][c] f32 -> out[b,t,c,l] f32, LDS tiled 32x32
__global__ __launch_bounds__(256) void tout_kernel(const float* __restrict__ x3,
        float* __restrict__ out) {
    __shared__ float tile[32][33];
    int bt = blockIdx.z;            // 0..15  (b*8+t)
    int l0 = blockIdx.y * 32;       // 0..255
    int c0 = blockIdx.x * 32;       // 0..511
    int tx = threadIdx.x, ty = threadIdx.y;   // 32 x 8
    #pragma unroll
    for (int i = 0; i < 4; i++) {
        int l = ty + i * 8;
        tile[l][tx] = x3[((size_t)bt * 256 + l0 + l) * 512 + c0 + tx];
    }
    __syncthreads();
    #pragma unroll
    for (int i = 0; i < 4; i++) {
        int cc = ty + i * 8;
        out[((size_t)bt * 512 + c0 + cc) * 256 + l0 + tx] = tile[tx][cc];
    }
}

// ---------------------------------------------------------------------------
extern "C" void kernel_launch(void* const* d_in, const int* in_sizes, int n_in,
                              void* d_out, int out_size, void* d_ws, size_t ws_size,
                              hipStream_t stream) {
    const float* in_feat = (const float*)d_in[0];
    const float* qkv_w  = (const float*)d_in[1];
    const float* qkv_b  = (const float*)d_in[2];
    const float* proj_w = (const float*)d_in[3];
    const float* proj_b = (const float*)d_in[4];
    const float* ln1_g  = (const float*)d_in[5];
    const float* ln1_b  = (const float*)d_in[6];
    const float* w1     = (const float*)d_in[7];
    const float* b1     = (const float*)d_in[8];
    const float* w2     = (const float*)d_in[9];
    const float* b2     = (const float*)d_in[10];
    const float* ln2_g  = (const float*)d_in[11];
    const float* ln2_b  = (const float*)d_in[12];

    char* ws = (char*)d_ws;
    float*  x    = (float*) (ws);              // 8 MB residual 1 (reused for final x3)
    float*  x2   = (float*) (ws + 8388608);    // 8 MB residual 2
    ushort* xln  = (ushort*)(ws + 16777216);   // 4 MB LN1 out (bf16)
    ushort* h2   = (ushort*)(ws + 20971520);   // 4 MB LN2 out (bf16)
    ushort* ao   = (ushort*)(ws + 25165824);   // 4 MB attention out (bf16)
    ushort* qkv  = (ushort*)(ws + 29360128);   // 12 MB qkv (bf16)
    ushort* gbuf = (ushort*)(ws + 41943040);   // 16 MB MLP hidden (bf16)

    // bf16-transposed weights live in d_out (8.39 MB), which tout_kernel fully
    // overwrites at step 8 -- zero extra workspace needed.
    char* scr = (char*)d_out;
    ushort* qkvT = (ushort*)(scr);             // 512*1536*2 = 1.5 MB
    ushort* projT = (ushort*)(scr + 1572864);  // 512*512*2  = 0.5 MB
    ushort* w1T  = (ushort*)(scr + 2097152);   // 512*2048*2 = 2 MB
    ushort* w2T  = (ushort*)(scr + 4194304);   // 2048*512*2 = 2 MB

    // 0) weight convert+transpose (all four in one launch)
    wtrans_kernel<<<3072, 256, 0, stream>>>(qkv_w, qkvT, proj_w, projT,
                                            w1, w1T, w2, w2T);
    // 1) transpose + LN1
    prep_kernel<<<4096, 512, 0, stream>>>(in_feat, ln1_g, ln1_b, x, xln);
    // 2) QKV: [4096,512] @ [512,1536] + b -> bf16
    gemm_kernel<EPI_BF16><<<dim3(12, 64), 256, 0, stream>>>(
        xln, qkvT, qkv_b, nullptr, nullptr, qkv, 4096, 1536, 512);
    // 3) attention (512 blocks x 512 threads, in-block key-split)
    flash_kernel<<<512, 512, 0, stream>>>(qkv, ao);
    // 4) proj + residual -> f32 x2
    gemm_kernel<EPI_F32RES><<<dim3(4, 64), 256, 0, stream>>>(
        ao, projT, proj_b, x, x2, nullptr, 4096, 512, 512);
    // 5) LN2
    ln2_kernel<<<4096, 512, 0, stream>>>(x2, ln2_g, ln2_b, h2);
    // 6) MLP up + GELU -> bf16
    gemm_kernel<EPI_GELU><<<dim3(16, 64), 256, 0, stream>>>(
        h2, w1T, b1, nullptr, nullptr, gbuf, 4096, 2048, 512);
    // 7) MLP down + residual -> f32 (into x buffer)
    gemm_kernel<EPI_F32RES><<<dim3(4, 64), 256, 0, stream>>>(
        gbuf, w2T, b2, x2, x, nullptr, 4096, 512, 2048);
    // 8) output transpose -> f32 out
    tout_kernel<<<dim3(16, 8, 16), dim3(32, 8), 0, stream>>>(x, (float*)d_out);
}

// Round 4
// 242.642 us; speedup vs baseline: 1.3559x; 1.0477x over previous
//
#include <hip/hip_runtime.h>
#include <stdint.h>
#include <math.h>

typedef __attribute__((ext_vector_type(8))) short short8;
typedef __attribute__((ext_vector_type(4))) float f32x4;
typedef __attribute__((ext_vector_type(4))) ushort ushort4v;

__device__ __forceinline__ ushort f2bf(float f) {
    union { float f; uint32_t i; } v; v.f = f;
    uint32_t r = v.i + 0x7FFFu + ((v.i >> 16) & 1u);
    return (ushort)(r >> 16);
}
__device__ __forceinline__ float bf2f(ushort u) {
    union { uint32_t i; float f; } v; v.i = ((uint32_t)u) << 16; return v.f;
}

// async global->LDS, 16B per lane. LDS dest is wave-uniform base + lane*16.
__device__ __forceinline__ void gload_lds16(const ushort* gp, ushort* lp) {
    __builtin_amdgcn_global_load_lds(
        (const __attribute__((address_space(1))) void*)gp,
        (__attribute__((address_space(3))) void*)lp, 16, 0, 0);
}

// ---------------------------------------------------------------------------
// Kernel 1: input transpose [B,T,C,L] (f32) -> x[token][c] (f32) + LN1 -> xln (bf16)
__global__ __launch_bounds__(512) void prep_kernel(const float* __restrict__ in,
        const float* __restrict__ g, const float* __restrict__ bta,
        float* __restrict__ x, ushort* __restrict__ xln) {
    int token = blockIdx.x;          // 0..4095
    int c = threadIdx.x;             // 0..511
    int b = token >> 11;
    int n = token & 2047;
    int t = n >> 8;
    int l = n & 255;
    size_t iidx = (((size_t)((b * 8 + t) * 512 + c)) << 8) + l;
    float v = in[iidx];
    x[(size_t)token * 512 + c] = v;

    float s = v, s2 = v * v;
    #pragma unroll
    for (int off = 32; off > 0; off >>= 1) {
        s  += __shfl_down(s, off, 64);
        s2 += __shfl_down(s2, off, 64);
    }
    __shared__ float ps[8], ps2[8];
    int wave = threadIdx.x >> 6, lane = threadIdx.x & 63;
    if (lane == 0) { ps[wave] = s; ps2[wave] = s2; }
    __syncthreads();
    float mu = 0.f, m2 = 0.f;
    #pragma unroll
    for (int i = 0; i < 8; i++) { mu += ps[i]; m2 += ps2[i]; }
    mu *= (1.0f / 512.0f); m2 *= (1.0f / 512.0f);
    float rs = rsqrtf(m2 - mu * mu + 1e-5f);
    float y = (v - mu) * rs * g[c] + bta[c];
    xln[(size_t)token * 512 + c] = f2bf(y);
}

// ---------------------------------------------------------------------------
// LN2 over f32 input -> bf16
__global__ __launch_bounds__(512) void ln2_kernel(const float* __restrict__ xin,
        const float* __restrict__ g, const float* __restrict__ bta,
        ushort* __restrict__ out) {
    int token = blockIdx.x;
    int c = threadIdx.x;
    float v = xin[(size_t)token * 512 + c];
    float s = v, s2 = v * v;
    #pragma unroll
    for (int off = 32; off > 0; off >>= 1) {
        s  += __shfl_down(s, off, 64);
        s2 += __shfl_down(s2, off, 64);
    }
    __shared__ float ps[8], ps2[8];
    int wave = threadIdx.x >> 6, lane = threadIdx.x & 63;
    if (lane == 0) { ps[wave] = s; ps2[wave] = s2; }
    __syncthreads();
    float mu = 0.f, m2 = 0.f;
    #pragma unroll
    for (int i = 0; i < 8; i++) { mu += ps[i]; m2 += ps2[i]; }
    mu *= (1.0f / 512.0f); m2 *= (1.0f / 512.0f);
    float rs = rsqrtf(m2 - mu * mu + 1e-5f);
    float y = (v - mu) * rs * g[c] + bta[c];
    out[(size_t)token * 512 + c] = f2bf(y);
}

// ---------------------------------------------------------------------------
// Fused weight transpose+convert: Bw f32 [K][N] -> Bt bf16 [N][K].
__global__ __launch_bounds__(256) void wtrans_kernel(
        const float* __restrict__ wa, ushort* __restrict__ ta,
        const float* __restrict__ wb, ushort* __restrict__ tb,
        const float* __restrict__ wc, ushort* __restrict__ tc,
        const float* __restrict__ wd, ushort* __restrict__ td) {
    __shared__ float tile[32][33];
    int bid = blockIdx.x;
    const float* W; ushort* T; int K, N, tn, tk;
    if (bid < 768)       { W = wa; T = ta; K = 512;  N = 1536; tn = bid % 48; tk = bid / 48; }
    else if (bid < 1024) { bid -= 768;  W = wb; T = tb; K = 512;  N = 512;  tn = bid % 16; tk = bid / 16; }
    else if (bid < 2048) { bid -= 1024; W = wc; T = tc; K = 512;  N = 2048; tn = bid % 64; tk = bid / 64; }
    else                 { bid -= 2048; W = wd; T = td; K = 2048; N = 512;  tn = bid % 16; tk = bid / 16; }
    int n0 = tn * 32, k0 = tk * 32;
    int tx = threadIdx.x & 31, ty = threadIdx.x >> 5;   // 32 x 8
    #pragma unroll
    for (int i = 0; i < 4; i++)
        tile[ty + i * 8][tx] = W[(size_t)(k0 + ty + i * 8) * N + n0 + tx];
    __syncthreads();
    #pragma unroll
    for (int i = 0; i < 4; i++) {
        int nn = ty + i * 8;
        T[(size_t)(n0 + nn) * K + k0 + tx] = f2bf(tile[tx][nn]);
    }
}

// ---------------------------------------------------------------------------
// MFMA GEMM, 2-phase double-buffered (T3-minimum): C = A[MxK] @ Bt[N][K] + bias.
// 64x128 tile, BK=64, 4 waves x (64x32). global_load_lds w16, XOR-swizzled src.
// One raw s_barrier + vmcnt(0) per K-tile -- next tile's loads fly under MFMA.
#define EPI_BF16   0
#define EPI_F32RES 1
#define EPI_GELU   2

template<int EPI>
__global__ __launch_bounds__(256) void gemm_kernel(
        const ushort* __restrict__ A, const ushort* __restrict__ Bt,
        const float* __restrict__ bias, const float* __restrict__ resid,
        float* __restrict__ outF, ushort* __restrict__ outB,
        int M, int N, int K) {
    __shared__ __align__(16) ushort As[2][64 * 64];    // 2 x 8 KB
    __shared__ __align__(16) ushort Bs[2][128 * 64];   // 2 x 16 KB
    int tid = threadIdx.x;
    int wave = tid >> 6, lane = tid & 63;
    int l16 = lane & 15, quad = lane >> 4;
    int wc = wave;
    int m0 = blockIdx.y * 64, n0 = blockIdx.x * 128;

    auto stage = [&](int bufi, int k0) {
        ushort* Ab = &As[bufi][0];
        ushort* Bb = &Bs[bufi][0];
        #pragma unroll
        for (int c = 0; c < 2; c++) {
            int e = c * 256 + tid;
            int row = e >> 3, ch = e & 7;
            int sc = ch ^ (row & 7);     // pre-swizzled source -> swizzled LDS
            gload_lds16(A + (size_t)(m0 + row) * K + k0 + sc * 8,
                        Ab + (size_t)(c * 256 + wave * 64) * 8);
        }
        #pragma unroll
        for (int c = 0; c < 4; c++) {
            int e = c * 256 + tid;
            int row = e >> 3, ch = e & 7;
            int sc = ch ^ (row & 7);
            gload_lds16(Bt + (size_t)(n0 + row) * K + k0 + sc * 8,
                        Bb + (size_t)(c * 256 + wave * 64) * 8);
        }
    };

    f32x4 acc[4][2] = {};
    stage(0, 0);
    asm volatile("s_waitcnt vmcnt(0)" ::: "memory");
    __builtin_amdgcn_s_barrier();
    __builtin_amdgcn_sched_barrier(0);
    int nt = K >> 6;
    for (int t = 0; t < nt; ++t) {
        int cur = t & 1;
        if (t + 1 < nt) stage(cur ^ 1, (t + 1) << 6);   // prefetch next tile
        const ushort* Ac = &As[cur][0];
        const ushort* Bc = &Bs[cur][0];
        #pragma unroll
        for (int kk = 0; kk < 2; kk++) {
            short8 af[4], bf[2];
            int slot = ((kk * 4 + quad) ^ (l16 & 7)) * 8;
            #pragma unroll
            for (int i = 0; i < 4; i++)
                af[i] = *(const short8*)&Ac[(i * 16 + l16) * 64 + slot];
            #pragma unroll
            for (int j = 0; j < 2; j++)
                bf[j] = *(const short8*)&Bc[(wc * 32 + j * 16 + l16) * 64 + slot];
            #pragma unroll
            for (int i = 0; i < 4; i++)
                #pragma unroll
                for (int j = 0; j < 2; j++)
                    acc[i][j] = __builtin_amdgcn_mfma_f32_16x16x32_bf16(af[i], bf[j], acc[i][j], 0, 0, 0);
        }
        if (t + 1 < nt) {
            asm volatile("s_waitcnt vmcnt(0)" ::: "memory");   // next tile landed
            __builtin_amdgcn_s_barrier();
            __builtin_amdgcn_sched_barrier(0);
        }
    }
    #pragma unroll
    for (int i = 0; i < 4; i++) {
        int row_base = m0 + i * 16 + quad * 4;
        #pragma unroll
        for (int j = 0; j < 2; j++) {
            int col = n0 + wc * 32 + j * 16 + l16;
            float bvf = bias[col];
            #pragma unroll
            for (int r = 0; r < 4; r++) {
                int row = row_base + r;
                float v = acc[i][j][r] + bvf;
                if constexpr (EPI == EPI_F32RES) {
                    outF[(size_t)row * N + col] = v + resid[(size_t)row * N + col];
                } else if constexpr (EPI == EPI_GELU) {
                    float gg = 0.5f * v * (1.0f + erff(v * 0.70710678118654752f));
                    outB[(size_t)row * N + col] = f2bf(gg);
                } else {
                    outB[(size_t)row * N + col] = f2bf(v);
                }
            }
        }
    }
}

// ---------------------------------------------------------------------------
// Flash attention, split-K in block, SWAPPED-OPERAND QK^T (T12 structure):
// sacc = mfma(K, Q) puts a full S-row per lane (q = l16, keys = s*16+quad*4+r).
// Softmax: 15 fmax + 2 shfl_xor (was 32 shfls). P staged via 4 packed
// ds_write_b64 into a half-size double-pumped Pt (was 16 scalar b16).
// PV = mfma(V^T, P): accO[s][r] = O^T[d = s*16+quad*4+r][q = l16]; the
// online-softmax rescale is lane-local. LDS 46.1 KB -> 3 blocks/CU.
__global__ __launch_bounds__(512, 6) void flash_kernel(const ushort* __restrict__ qkv,
        ushort* __restrict__ o) {
    __shared__ __align__(16) char smem[47232];
    auto Ks  = (ushort (*)[64][72])smem;              // [kh][key][d]   18432 B
    auto Vt  = (ushort (*)[4640])(smem + 18432);      // [kh][VT(d,key)] 18560 B
    auto Pt  = (ushort (*)[16][40])(smem + 36992);    // [wave][q][32key+pad] 10240 B
    auto cbuf = (float (*)[18][64])smem;              // combine buffer (aliased)
    // VT(d,key) = d*72 + (d>>4)*8 + key

    int tid = threadIdx.x;
    int wave = tid >> 6, lane = tid & 63;
    int kh = wave >> 2;          // key half this wave owns
    int wq = wave & 3;           // 16-q-row group
    int l16 = lane & 15, quad = lane >> 4;
    int bidx = blockIdx.x;
    int qt = bidx & 31;
    int h = (bidx >> 5) & 7;
    int b = bidx >> 8;
    int q0 = qt * 64;
    const size_t base = (size_t)b * 2048 * 1536;

    int htid = tid & 255;
    int srow = htid >> 2;            // key row 0..63
    int sg   = htid & 3;             // d-chunk 0..3
    int sdb  = sg * 16;
    const ushort* kgbase = qkv + base + 512  + h * 64 + sdb;
    const ushort* vgbase = qkv + base + 1024 + h * 64 + sdb;
    int vldsoff = sdb * 72 + sg * 8 + srow;

    short8 aq[2];
    {
        int qrow = q0 + wq * 16 + l16;
        const ushort* qp = qkv + base + (size_t)qrow * 1536 + h * 64;
        aq[0] = *(const short8*)(qp + quad * 8);
        aq[1] = *(const short8*)(qp + 32 + quad * 8);
    }
    f32x4 accO[4] = {};
    float mrow = -INFINITY, lrow = 0.f;   // per-lane state for q = l16

    {   // prologue: stage tile 0
        int kb = kh * 1024;
        const ushort* kp = kgbase + (size_t)(kb + srow) * 1536;
        short8 k0 = *(const short8*)kp;
        short8 k1 = *(const short8*)(kp + 8);
        const ushort* vp = vgbase + (size_t)(kb + srow) * 1536;
        short8 v0 = *(const short8*)vp;
        short8 v1 = *(const short8*)(vp + 8);
        *(short8*)&Ks[kh][srow][sdb]     = k0;
        *(short8*)&Ks[kh][srow][sdb + 8] = k1;
        #pragma unroll
        for (int i = 0; i < 8; i++) Vt[kh][vldsoff + i * 72] = (ushort)v0[i];
        #pragma unroll
        for (int i = 0; i < 8; i++) Vt[kh][vldsoff + (8 + i) * 72] = (ushort)v1[i];
    }
    __syncthreads();

    for (int it = 0; it < 16; ++it) {
        short8 nk0, nk1, nv0, nv1;
        bool pre = (it < 15);
        if (pre) {   // prefetch next tile -> regs; latency hides under compute
            int kb = kh * 1024 + (it + 1) * 64;
            const ushort* kp = kgbase + (size_t)(kb + srow) * 1536;
            nk0 = *(const short8*)kp;
            nk1 = *(const short8*)(kp + 8);
            const ushort* vp = vgbase + (size_t)(kb + srow) * 1536;
            nv0 = *(const short8*)vp;
            nv1 = *(const short8*)(vp + 8);
        }
        // S^T = K Q^T : lane (l16,quad) gets S[key=s*16+quad*4+r][q=l16]
        f32x4 sacc[4] = {};
        __builtin_amdgcn_s_setprio(1);
        #pragma unroll
        for (int c = 0; c < 2; c++) {
            #pragma unroll
            for (int s = 0; s < 4; s++) {
                short8 kf = *(short8*)&Ks[kh][s * 16 + l16][c * 32 + quad * 8];
                sacc[s] = __builtin_amdgcn_mfma_f32_16x16x32_bf16(kf, aq[c], sacc[s], 0, 0, 0);
            }
        }
        __builtin_amdgcn_s_setprio(0);
        // online softmax: per-lane row, reduce across the 4 quads
        float tm = sacc[0][0];
        #pragma unroll
        for (int s = 0; s < 4; s++)
            #pragma unroll
            for (int r = 0; r < 4; r++) tm = fmaxf(tm, sacc[s][r]);
        tm = fmaxf(tm, __shfl_xor(tm, 16, 64));
        tm = fmaxf(tm, __shfl_xor(tm, 32, 64));
        float mn = fmaxf(mrow, tm * 0.125f);
        float al = __expf(mrow - mn);
        float rsum = 0.f;
        ushort4v w4[4];
        #pragma unroll
        for (int s = 0; s < 4; s++)
            #pragma unroll
            for (int r = 0; r < 4; r++) {
                float pv = __expf(sacc[s][r] * 0.125f - mn);
                rsum += pv;
                w4[s][r] = f2bf(pv);
            }
        rsum += __shfl_xor(rsum, 16, 64);
        rsum += __shfl_xor(rsum, 32, 64);
        lrow = lrow * al + rsum;
        mrow = mn;
        #pragma unroll
        for (int s = 0; s < 4; s++)
            #pragma unroll
            for (int r = 0; r < 4; r++) accO[s][r] *= al;
        // P -> Pt (packed b64), double-pumped half tile; PV = mfma(V^T, P)
        *(ushort4v*)&Pt[wave][l16][quad * 4]      = w4[0];
        *(ushort4v*)&Pt[wave][l16][16 + quad * 4] = w4[1];
        {
            short8 ap = *(short8*)&Pt[wave][l16][quad * 8];
            __builtin_amdgcn_s_setprio(1);
            #pragma unroll
            for (int s = 0; s < 4; s++) {
                short8 vf = *(short8*)&Vt[kh][(s * 16 + l16) * 72 + s * 8 + quad * 8];
                accO[s] = __builtin_amdgcn_mfma_f32_16x16x32_bf16(vf, ap, accO[s], 0, 0, 0);
            }
            __builtin_amdgcn_s_setprio(0);
        }
        *(ushort4v*)&Pt[wave][l16][quad * 4]      = w4[2];
        *(ushort4v*)&Pt[wave][l16][16 + quad * 4] = w4[3];
        {
            short8 ap = *(short8*)&Pt[wave][l16][quad * 8];
            __builtin_amdgcn_s_setprio(1);
            #pragma unroll
            for (int s = 0; s < 4; s++) {
                short8 vf = *(short8*)&Vt[kh][(s * 16 + l16) * 72 + s * 8 + 32 + quad * 8];
                accO[s] = __builtin_amdgcn_mfma_f32_16x16x32_bf16(vf, ap, accO[s], 0, 0, 0);
            }
            __builtin_amdgcn_s_setprio(0);
        }
        __syncthreads();   // all waves done reading Ks/Vt tile it
        if (pre) {
            *(short8*)&Ks[kh][srow][sdb]     = nk0;
            *(short8*)&Ks[kh][srow][sdb + 8] = nk1;
            #pragma unroll
            for (int i = 0; i < 8; i++) Vt[kh][vldsoff + i * 72] = (ushort)nv0[i];
            #pragma unroll
            for (int i = 0; i < 8; i++) Vt[kh][vldsoff + (8 + i) * 72] = (ushort)nv1[i];
        }
        __syncthreads();
    }
    // ---- merge key-half partials (wave w with wave w+4); state is per-lane ----
    if (kh == 1) {
        cbuf[wq][0][lane] = mrow;
        cbuf[wq][1][lane] = lrow;
        #pragma unroll
        for (int s = 0; s < 4; s++)
            #pragma unroll
            for (int r = 0; r < 4; r++)
                cbuf[wq][2 + s * 4 + r][lane] = accO[s][r];
    }
    __syncthreads();
    if (kh == 0) {
        float m1 = cbuf[wq][0][lane];
        float l1 = cbuf[wq][1][lane];
        float mn = fmaxf(mrow, m1);
        float a0 = __expf(mrow - mn);
        float a1 = __expf(m1 - mn);
        float rl = 1.0f / (lrow * a0 + l1 * a1);
        int qrow = q0 + wq * 16 + l16;
        #pragma unroll
        for (int s = 0; s < 4; s++) {
            ushort4v ov4;
            #pragma unroll
            for (int r = 0; r < 4; r++) {
                float ov = (accO[s][r] * a0 + cbuf[wq][2 + s * 4 + r][lane] * a1) * rl;
                ov4[r] = f2bf(ov);
            }
            // d = s*16 + quad*4 + r: 4 consecutive -> packed 8B store
            *(ushort4v*)&o[((size_t)(b * 2048 + qrow)) * 512 + h * 64 + s * 16 + quad * 4] = ov4;
        }
    }
}

// ---------------------------------------------------------------------------
// Output transpose: x3[token][c] f32 -> out[b,t,c,l] f32, LDS tiled 32x32
__global__ __launch_bounds__(256) void tout_kernel(const float* __restrict__ x3,
        float* __restrict__ out) {
    __shared__ float tile[32][33];
    int bt = blockIdx.z;
    int l0 = blockIdx.y * 32;
    int c0 = blockIdx.x * 32;
    int tx = threadIdx.x, ty = threadIdx.y;   // 32 x 8
    #pragma unroll
    for (int i = 0; i < 4; i++) {
        int l = ty + i * 8;
        tile[l][tx] = x3[((size_t)bt * 256 + l0 + l) * 512 + c0 + tx];
    }
    __syncthreads();
    #pragma unroll
    for (int i = 0; i < 4; i++) {
        int cc = ty + i * 8;
        out[((size_t)bt * 512 + c0 + cc) * 256 + l0 + tx] = tile[tx][cc];
    }
}

// ---------------------------------------------------------------------------
extern "C" void kernel_launch(void* const* d_in, const int* in_sizes, int n_in,
                              void* d_out, int out_size, void* d_ws, size_t ws_size,
                              hipStream_t stream) {
    const float* in_feat = (const float*)d_in[0];
    const float* qkv_w  = (const float*)d_in[1];
    const float* qkv_b  = (const float*)d_in[2];
    const float* proj_w = (const float*)d_in[3];
    const float* proj_b = (const float*)d_in[4];
    const float* ln1_g  = (const float*)d_in[5];
    const float* ln1_b  = (const float*)d_in[6];
    const float* w1     = (const float*)d_in[7];
    const float* b1     = (const float*)d_in[8];
    const float* w2     = (const float*)d_in[9];
    const float* b2     = (const float*)d_in[10];
    const float* ln2_g  = (const float*)d_in[11];
    const float* ln2_b  = (const float*)d_in[12];

    char* ws = (char*)d_ws;
    float*  x    = (float*) (ws);              // 8 MB residual 1
    float*  x2   = (float*) (ws + 8388608);    // 8 MB residual 2
    ushort* xln  = (ushort*)(ws + 16777216);   // 4 MB LN1 out
    ushort* h2   = (ushort*)(ws + 20971520);   // 4 MB LN2 out
    ushort* ao   = (ushort*)(ws + 25165824);   // 4 MB attention out
    ushort* qkv  = (ushort*)(ws + 29360128);   // 12 MB qkv
    ushort* gbuf = (ushort*)(ws + 41943040);   // 16 MB MLP hidden

    // bf16-transposed weights live in d_out (overwritten by tout at step 8)
    char* scr = (char*)d_out;
    ushort* qkvT = (ushort*)(scr);             // 1.5 MB
    ushort* projT = (ushort*)(scr + 1572864);  // 0.5 MB
    ushort* w1T  = (ushort*)(scr + 2097152);   // 2 MB
    ushort* w2T  = (ushort*)(scr + 4194304);   // 2 MB

    wtrans_kernel<<<3072, 256, 0, stream>>>(qkv_w, qkvT, proj_w, projT,
                                            w1, w1T, w2, w2T);
    prep_kernel<<<4096, 512, 0, stream>>>(in_feat, ln1_g, ln1_b, x, xln);
    gemm_kernel<EPI_BF16><<<dim3(12, 64), 256, 0, stream>>>(
        xln, qkvT, qkv_b, nullptr, nullptr, qkv, 4096, 1536, 512);
    flash_kernel<<<512, 512, 0, stream>>>(qkv, ao);
    gemm_kernel<EPI_F32RES><<<dim3(4, 64), 256, 0, stream>>>(
        ao, projT, proj_b, x, x2, nullptr, 4096, 512, 512);
    ln2_kernel<<<4096, 512, 0, stream>>>(x2, ln2_g, ln2_b, h2);
    gemm_kernel<EPI_GELU><<<dim3(16, 64), 256, 0, stream>>>(
        h2, w1T, b1, nullptr, nullptr, gbuf, 4096, 2048, 512);
    gemm_kernel<EPI_F32RES><<<dim3(4, 64), 256, 0, stream>>>(
        gbuf, w2T, b2, x2, x, nullptr, 4096, 512, 2048);
    tout_kernel<<<dim3(16, 8, 16), dim3(32, 8), 0, stream>>>(x, (float*)d_out);
}